// Round 10
// baseline (50.325 us; speedup 1.0000x reference)
//
#include <hip/hip_runtime.h>
#include <math.h>

typedef unsigned long long u64;

#define B 512
#define M 4096
#define T 48
#define BG 8                 // b's per k_main block
#define MTILE 256            // m's per k_main block (1 per thread)
#define NMB (M / MTILE)      // 16 m-tiles

// ws layout (bytes):
//   [0, 64 KiB)        pval[b][mt]: packed (float_bits(dist)<<32 | m), u64
//   [64 KiB, +1.5 MiB) memT[t][m]: float2 (transposed memory)

// ---- Kernel 0: transpose memory (M,T,2) -> memT[t][m]; zero loss slot -----
__global__ __launch_bounds__(256) void k_prep(const float* __restrict__ memory,
                                              float2* __restrict__ memT,
                                              float* __restrict__ out0) {
    int i = blockIdx.x * 256 + threadIdx.x;        // < M*T = 196608
    if (i == 0) out0[0] = 0.0f;
    int m = i / T, t = i - m * T;
    memT[t * M + m] = ((const float2*)memory)[i];  // coalesced read
}

// ---- Kernel 1: distance. thread = m; 8 b's reused from registers ----------
// Per t: 1 coalesced float2 load (only per-lane memory op) + 4 uniform
// b128 LDS broadcasts (targets) + 8 register-resident terms.
__global__ __launch_bounds__(256) void k_main(const float* __restrict__ target,
                                              const float2* __restrict__ memT,
                                              u64* __restrict__ pval) {
    const int tid = threadIdx.x;
    const int mt  = blockIdx.x;
    const int m   = mt * MTILE + tid;
    const int b0  = blockIdx.y * BG;

    // tgL[t][b_local][c]: 48*8*2 floats = 3 KB, staged coalesced
    __shared__ float4 tgL4[T * BG / 2];            // [t*4 + k], k = b-pair
    __shared__ u64    su[4][BG];
    {
        float* tgw = (float*)tgL4;
        const float* src = target + (size_t)b0 * (T * 2);
        for (int i = tid; i < BG * T * 2; i += 256) {
            int bl = i / (T * 2), r = i - bl * (T * 2);
            int t = r >> 1, c = r & 1;
            tgw[t * (2 * BG) + bl * 2 + c] = src[i];
        }
    }
    __syncthreads();

    float acc[BG];
#pragma unroll
    for (int bi = 0; bi < BG; ++bi) acc[bi] = 0.f;

#pragma unroll 4
    for (int t = 0; t < T; ++t) {
        float2 mv = memT[t * M + m];               // coalesced 8B/lane
#pragma unroll
        for (int k = 0; k < 4; ++k) {
            float4 g = tgL4[t * 4 + k];            // uniform -> LDS broadcast
            float dx0 = mv.x - g.x, dy0 = mv.y - g.y;
            float dx1 = mv.x - g.z, dy1 = mv.y - g.w;
            acc[2 * k]     += __builtin_amdgcn_sqrtf(fmaf(dx0, dx0, dy0 * dy0));
            acc[2 * k + 1] += __builtin_amdgcn_sqrtf(fmaf(dx1, dx1, dy1 * dy1));
        }
    }

    // per-b argmin: wave shfl-reduce over 64 m-lanes, then cross-wave via LDS
    const int lane = tid & 63, w = tid >> 6;
#pragma unroll
    for (int bi = 0; bi < BG; ++bi) {
        u64 p = ((u64)__float_as_uint(acc[bi]) << 32) | (unsigned int)m;
#pragma unroll
        for (int s = 32; s > 0; s >>= 1) {
            u64 o = __shfl_down(p, s);
            if (o < p) p = o;                      // lexmin keeps lowest m on tie
        }
        if (lane == 0) su[w][bi] = p;
    }
    __syncthreads();
    if (tid < BG) {
        u64 p = su[0][tid];
        if (su[1][tid] < p) p = su[1][tid];
        if (su[2][tid] < p) p = su[2][tid];
        if (su[3][tid] < p) p = su[3][tid];
        pval[(size_t)(b0 + tid) * NMB + mt] = p;
    }
}

// ---- Kernel 2: block per b: final argmin + LSE + NLL + mean ---------------
__global__ __launch_bounds__(256) void k_post(const float* __restrict__ preds,
                                              const u64* __restrict__ pval,
                                              float* __restrict__ out) {
    const int b = blockIdx.x, tid = threadIdx.x;
    __shared__ float red[256];
    __shared__ int   sidx;

    if (tid < 64) {                                // final argmin over 16 m-tiles
        u64 p = (tid < NMB) ? pval[(size_t)b * NMB + tid] : 0xFFFFFFFFFFFFFFFFULL;
#pragma unroll
        for (int s = 8; s > 0; s >>= 1) {
            u64 o = __shfl_down(p, s);
            if (o < p) p = o;
        }
        if (tid == 0) sidx = (int)(unsigned int)(p & 0xFFFFFFFFULL);
    }

    const float4* row = (const float4*)(preds + (size_t)b * M);  // 1024 float4
    float4 v[4];
    float mx = -INFINITY;
#pragma unroll
    for (int j = 0; j < 4; ++j) {
        v[j] = row[tid + j * 256];
        mx = fmaxf(mx, fmaxf(fmaxf(v[j].x, v[j].y), fmaxf(v[j].z, v[j].w)));
    }
    red[tid] = mx; __syncthreads();
    for (int s = 128; s > 0; s >>= 1) {
        if (tid < s) red[tid] = fmaxf(red[tid], red[tid + s]);
        __syncthreads();
    }
    mx = red[0];
    __syncthreads();

    float sum = 0.f;
#pragma unroll
    for (int j = 0; j < 4; ++j)
        sum += expf(v[j].x - mx) + expf(v[j].y - mx) + expf(v[j].z - mx) + expf(v[j].w - mx);
    red[tid] = sum; __syncthreads();
    for (int s = 128; s > 0; s >>= 1) {
        if (tid < s) red[tid] += red[tid + s];
        __syncthreads();
    }

    if (tid == 0) {
        float lse = mx + logf(red[0]);
        float nll = lse - preds[(size_t)b * M + sidx];
        atomicAdd(out, nll * (1.0f / B));          // out[0] zeroed by k_prep
        out[1 + b] = (float)sidx;
    }
}

extern "C" void kernel_launch(void* const* d_in, const int* in_sizes, int n_in,
                              void* d_out, int out_size, void* d_ws, size_t ws_size,
                              hipStream_t stream) {
    const float* preds  = (const float*)d_in[0];  // (512, 4096)
    const float* target = (const float*)d_in[1];  // (512, 1, 48, 2)
    const float* memory = (const float*)d_in[2];  // (4096, 48, 2)
    float* out = (float*)d_out;                   // [loss, idx[512]]

    char* ws = (char*)d_ws;
    u64* pval    = (u64*)ws;                      // 512*16*8 = 64 KiB
    float2* memT = (float2*)(ws + 64 * 1024);     // 1.5 MiB

    k_prep<<<(M * T) / 256, 256, 0, stream>>>(memory, memT, out);
    dim3 g1(NMB, B / BG);                         // 16 x 64 = 1024 blocks
    k_main<<<g1, 256, 0, stream>>>(target, memT, pval);
    k_post<<<B, 256, 0, stream>>>(preds, pval, out);
}